// Round 10
// baseline (214.049 us; speedup 1.0000x reference)
//
#include <hip/hip_runtime.h>

// Blur = separable 4-tap FIR, taps [0.25,0.75,0.75,0.25], zero-pad (2,1)/(2,1).
// R8 deferred-store NT pipeline + SERPENTINE strips: odd waves sweep their
// 64-row strip bottom-up, so the 3 shared halo rows at every strip boundary
// are read by both neighbor waves at the SAME phase (start/start or end/end).
// Those 6 boundary offsets use cached loads (they're the only reused lines);
// all bulk traffic stays non-temporal (no allocate/evict churn). Boundaries
// are intra-block -> the two readers are always co-resident.

constexpr int W = 256;
constexpr int H = 256;
constexpr float F0 = 0.25f;
constexpr float F1 = 0.75f;

typedef float f32x4 __attribute__((ext_vector_type(4)));

// Horizontal 4-tap pass. Lane l holds cols [4l,4l+3]; halo via 3 shuffles.
__device__ __forceinline__ f32x4 hfilt(const f32x4 v, const int lane) {
    float xl2 = __shfl_up(v.z, 1);
    float xl1 = __shfl_up(v.w, 1);
    float xr  = __shfl_down(v.x, 1);
    if (lane == 0)  { xl2 = 0.0f; xl1 = 0.0f; }
    if (lane == 63) { xr = 0.0f; }
    f32x4 h;
    h.x = F0 * xl2 + F1 * xl1 + F1 * v.x + F0 * v.y;
    h.y = F0 * xl1 + F1 * v.x + F1 * v.y + F0 * v.z;
    h.z = F0 * v.x + F1 * v.y + F1 * v.z + F0 * v.w;
    h.w = F0 * v.y + F1 * v.z + F1 * v.w + F0 * xr;
    return h;
}

// Vertical 4-tap: out = F0*(A+D) + F1*(B+C) — symmetric in (A,D) and (B,C),
// so the same formula serves both sweep directions.
__device__ __forceinline__ f32x4 vfilt(const f32x4 A, const f32x4 B,
                                       const f32x4 C, const f32x4 D) {
    f32x4 o;
    o.x = F0 * (A.x + D.x) + F1 * (B.x + C.x);
    o.y = F0 * (A.y + D.y) + F1 * (B.y + C.y);
    o.z = F0 * (A.z + D.z) + F1 * (B.z + C.z);
    o.w = F0 * (A.w + D.w) + F1 * (B.w + C.w);
    return o;
}

// One 64-row strip, logical steps in down-convention; DOWN=false mirrors via
// load offset 62-k, store offset 63-k (asymmetric pad shifts the two maps).
template <bool DOWN>
__device__ __forceinline__ void do_strip(const float* __restrict__ xp,
                                         float* __restrict__ op,
                                         const int r0, const int lane,
                                         const int col) {
    auto loadrow = [&](int k) -> f32x4 {
        const int off = DOWN ? k : 62 - k;       // physical strip offset
        const int i = r0 + off;
        if ((unsigned)i >= (unsigned)H) return f32x4{0.f, 0.f, 0.f, 0.f};
        const f32x4* p = reinterpret_cast<const f32x4*>(xp + i * W + col);
        if (off <= 0 || off >= 62)               // boundary rows (shared): cached
            return *p;
        return __builtin_nontemporal_load(p);    // bulk: touch-once, stream
    };
    auto storerow = [&](int k, const f32x4 o) {
        const int i = r0 + (DOWN ? k : 63 - k);
        __builtin_nontemporal_store(o, reinterpret_cast<f32x4*>(op + i * W + col));
    };

    // Window prime: logical rows -2,-1,0 (out-of-range rows are zero-pad).
    f32x4 A = hfilt(loadrow(-2), lane);
    f32x4 B = hfilt(loadrow(-1), lane);
    f32x4 C = hfilt(loadrow(0), lane);

    // Two 4-row raw-input buffers, 8 rows in flight (named: static indexing).
    f32x4 a0 = loadrow(1), a1 = loadrow(2), a2 = loadrow(3), a3 = loadrow(4);
    f32x4 b0 = loadrow(5), b1 = loadrow(6), b2 = loadrow(7), b3 = loadrow(8);

#pragma unroll
    for (int g = 0; g < 8; ++g) {
        const int base = 8 * g;        // logical outputs base..base+7

        // ---- half 1: consume a (logical rows base+1..base+4)
        f32x4 D0 = hfilt(a0, lane), D1 = hfilt(a1, lane),
              D2 = hfilt(a2, lane), D3 = hfilt(a3, lane);
        f32x4 o0 = vfilt(A,  B,  C,  D0);
        f32x4 o1 = vfilt(B,  C,  D0, D1);
        f32x4 o2 = vfilt(C,  D0, D1, D2);
        f32x4 o3 = vfilt(D0, D1, D2, D3);
        A = D1; B = D2; C = D3;
        if (g < 7) {  // refill a (logical base+9..base+12) BEFORE the stores
            a0 = loadrow(base + 9);  a1 = loadrow(base + 10);
            a2 = loadrow(base + 11); a3 = loadrow(base + 12);
        }
        storerow(base,     o0); storerow(base + 1, o1);
        storerow(base + 2, o2); storerow(base + 3, o3);

        // ---- half 2: consume b (logical rows base+5..base+8)
        f32x4 E0 = hfilt(b0, lane), E1 = hfilt(b1, lane),
              E2 = hfilt(b2, lane), E3 = hfilt(b3, lane);
        f32x4 p0 = vfilt(A,  B,  C,  E0);
        f32x4 p1 = vfilt(B,  C,  E0, E1);
        f32x4 p2 = vfilt(C,  E0, E1, E2);
        f32x4 p3 = vfilt(E0, E1, E2, E3);
        A = E1; B = E2; C = E3;
        if (g < 7) {  // refill b (logical base+13..base+16) BEFORE the stores
            b0 = loadrow(base + 13); b1 = loadrow(base + 14);
            b2 = loadrow(base + 15); b3 = loadrow(base + 16);
        }
        storerow(base + 4, p0); storerow(base + 5, p1);
        storerow(base + 6, p2); storerow(base + 7, p3);
    }
}

__global__ __launch_bounds__(256) void blur_kernel(const float* __restrict__ x,
                                                   float* __restrict__ out) {
    const int plane = blockIdx.x;
    const int wave  = threadIdx.x >> 6;
    const int lane  = threadIdx.x & 63;
    const float* xp = x + (size_t)plane * (H * W);
    float*       op = out + (size_t)plane * (H * W);
    const int r0  = wave * 64;
    const int col = lane * 4;

    if (wave & 1)  // serpentine: odd strips sweep bottom-up (wave-uniform branch)
        do_strip<false>(xp, op, r0, lane, col);
    else
        do_strip<true>(xp, op, r0, lane, col);
}

extern "C" void kernel_launch(void* const* d_in, const int* in_sizes, int n_in,
                              void* d_out, int out_size, void* d_ws, size_t ws_size,
                              hipStream_t stream) {
    const float* x = (const float*)d_in[0];
    float* o = (float*)d_out;
    const int planes = in_sizes[0] / (H * W);  // N*C = 2048
    blur_kernel<<<planes, 256, 0, stream>>>(x, o);
}

// Round 11
// 213.949 us; speedup vs baseline: 1.0005x; 1.0005x over previous
//
#include <hip/hip_runtime.h>

// Blur = separable 4-tap FIR, taps [0.25,0.75,0.75,0.25], zero-pad (2,1)/(2,1).
// R8 deferred-store NT pipeline, 128-row strips: block = 4 waves = 2 planes;
// halo re-read drops from 3/64 to 3/128 of input rows, and the 3 boundary rows
// (physical 126..128) use CACHED loads so the co-resident neighbor wave's
// re-read is an L2 hit (NT bulk traffic doesn't churn L2, so they survive).
// 4096 waves = 16/CU — the level R5 proved sufficient (R9's 8/CU was not).

constexpr int W = 256;
constexpr int H = 256;
constexpr float F0 = 0.25f;
constexpr float F1 = 0.75f;

typedef float f32x4 __attribute__((ext_vector_type(4)));

// Horizontal 4-tap pass. Lane l holds cols [4l,4l+3]; halo via 3 shuffles.
__device__ __forceinline__ f32x4 hfilt(const f32x4 v, const int lane) {
    float xl2 = __shfl_up(v.z, 1);
    float xl1 = __shfl_up(v.w, 1);
    float xr  = __shfl_down(v.x, 1);
    if (lane == 0)  { xl2 = 0.0f; xl1 = 0.0f; }
    if (lane == 63) { xr = 0.0f; }
    f32x4 h;
    h.x = F0 * xl2 + F1 * xl1 + F1 * v.x + F0 * v.y;
    h.y = F0 * xl1 + F1 * v.x + F1 * v.y + F0 * v.z;
    h.z = F0 * v.x + F1 * v.y + F1 * v.z + F0 * v.w;
    h.w = F0 * v.y + F1 * v.z + F1 * v.w + F0 * xr;
    return h;
}

// Vertical 4-tap: out = F0*(A+D) + F1*(B+C), componentwise.
__device__ __forceinline__ f32x4 vfilt(const f32x4 A, const f32x4 B,
                                       const f32x4 C, const f32x4 D) {
    f32x4 o;
    o.x = F0 * (A.x + D.x) + F1 * (B.x + C.x);
    o.y = F0 * (A.y + D.y) + F1 * (B.y + C.y);
    o.z = F0 * (A.z + D.z) + F1 * (B.z + C.z);
    o.w = F0 * (A.w + D.w) + F1 * (B.w + C.w);
    return o;
}

__global__ __launch_bounds__(256) void blur_kernel(const float* __restrict__ x,
                                                   float* __restrict__ out) {
    const int wave  = threadIdx.x >> 6;
    const int lane  = threadIdx.x & 63;
    const int strip = blockIdx.x * 4 + wave;   // 4096 strips of 128 rows
    const int plane = strip >> 1;
    const int r0    = (strip & 1) * 128;
    const float* xp = x + (size_t)plane * (H * W);
    float*       op = out + (size_t)plane * (H * W);
    const int col = lane * 4;

    auto loadrow = [&](int i) -> f32x4 {
        if ((unsigned)i >= (unsigned)H) return f32x4{0.f, 0.f, 0.f, 0.f};
        const f32x4* p = reinterpret_cast<const f32x4*>(xp + i * W + col);
        if (i >= 126 && i <= 128)              // inter-strip boundary: cached
            return *p;                         // (wave-uniform branch)
        return __builtin_nontemporal_load(p);  // bulk: touch-once, stream
    };
    auto storerow = [&](int i, const f32x4 o) {
        __builtin_nontemporal_store(o, reinterpret_cast<f32x4*>(op + i * W + col));
    };

    // Rolling window of hfilt'd rows: out io needs h(io-2),h(io-1),h(io),h(io+1).
    f32x4 A = hfilt(loadrow(r0 - 2), lane);
    f32x4 B = hfilt(loadrow(r0 - 1), lane);
    f32x4 C = hfilt(loadrow(r0), lane);

    // Two 4-row raw-input buffers, 8 rows in flight (named: static indexing).
    f32x4 a0 = loadrow(r0 + 1), a1 = loadrow(r0 + 2),
          a2 = loadrow(r0 + 3), a3 = loadrow(r0 + 4);
    f32x4 b0 = loadrow(r0 + 5), b1 = loadrow(r0 + 6),
          b2 = loadrow(r0 + 7), b3 = loadrow(r0 + 8);

#pragma unroll 2
    for (int g = 0; g < 16; ++g) {
        const int base = r0 + 8 * g;   // outputs base..base+7 this group
        const bool refill = (g < 15);

        // ---- half 1: consume a (rows base+1..base+4), outputs base..base+3
        f32x4 D0 = hfilt(a0, lane), D1 = hfilt(a1, lane),
              D2 = hfilt(a2, lane), D3 = hfilt(a3, lane);
        f32x4 o0 = vfilt(A,  B,  C,  D0);
        f32x4 o1 = vfilt(B,  C,  D0, D1);
        f32x4 o2 = vfilt(C,  D0, D1, D2);
        f32x4 o3 = vfilt(D0, D1, D2, D3);
        A = D1; B = D2; C = D3;
        if (refill) {  // rows base+9..base+12 BEFORE the stores
            a0 = loadrow(base + 9);  a1 = loadrow(base + 10);
            a2 = loadrow(base + 11); a3 = loadrow(base + 12);
        }
        storerow(base,     o0); storerow(base + 1, o1);
        storerow(base + 2, o2); storerow(base + 3, o3);

        // ---- half 2: consume b (rows base+5..base+8), outputs base+4..base+7
        f32x4 E0 = hfilt(b0, lane), E1 = hfilt(b1, lane),
              E2 = hfilt(b2, lane), E3 = hfilt(b3, lane);
        f32x4 p0 = vfilt(A,  B,  C,  E0);
        f32x4 p1 = vfilt(B,  C,  E0, E1);
        f32x4 p2 = vfilt(C,  E0, E1, E2);
        f32x4 p3 = vfilt(E0, E1, E2, E3);
        A = E1; B = E2; C = E3;
        if (refill) {  // rows base+13..base+16 BEFORE the stores
            b0 = loadrow(base + 13); b1 = loadrow(base + 14);
            b2 = loadrow(base + 15); b3 = loadrow(base + 16);
        }
        storerow(base + 4, p0); storerow(base + 5, p1);
        storerow(base + 6, p2); storerow(base + 7, p3);
    }
}

extern "C" void kernel_launch(void* const* d_in, const int* in_sizes, int n_in,
                              void* d_out, int out_size, void* d_ws, size_t ws_size,
                              hipStream_t stream) {
    const float* x = (const float*)d_in[0];
    float* o = (float*)d_out;
    const int planes = in_sizes[0] / (H * W);  // N*C = 2048
    blur_kernel<<<planes / 2, 256, 0, stream>>>(x, o);
}

// Round 12
// 201.920 us; speedup vs baseline: 1.0601x; 1.0596x over previous
//
#include <hip/hip_runtime.h>

// Blur = separable 4-tap FIR, taps [0.25,0.75,0.75,0.25], zero-pad (2,1)/(2,1).
// R8 deferred-store NT pipeline (unchanged hot loop, 32 waves/CU) + LDS halo
// sharing: each wave stash-loads its rows {0,62,63} (the only rows a neighbor
// wave needs), writes them to LDS, one __syncthreads, then the pipeline reads
// offsets {-2,-1,0,62,63,64} from LDS instead of HBM. Every input row is
// fetched from HBM exactly once -> FETCH = ideal 537 MB (R8 re-fetched +4.7%).

constexpr int W = 256;
constexpr int H = 256;
constexpr float F0 = 0.25f;
constexpr float F1 = 0.75f;

typedef float f32x4 __attribute__((ext_vector_type(4)));

// Horizontal 4-tap pass. Lane l holds cols [4l,4l+3]; halo via 3 shuffles.
__device__ __forceinline__ f32x4 hfilt(const f32x4 v, const int lane) {
    float xl2 = __shfl_up(v.z, 1);
    float xl1 = __shfl_up(v.w, 1);
    float xr  = __shfl_down(v.x, 1);
    if (lane == 0)  { xl2 = 0.0f; xl1 = 0.0f; }
    if (lane == 63) { xr = 0.0f; }
    f32x4 h;
    h.x = F0 * xl2 + F1 * xl1 + F1 * v.x + F0 * v.y;
    h.y = F0 * xl1 + F1 * v.x + F1 * v.y + F0 * v.z;
    h.z = F0 * v.x + F1 * v.y + F1 * v.z + F0 * v.w;
    h.w = F0 * v.y + F1 * v.z + F1 * v.w + F0 * xr;
    return h;
}

// Vertical 4-tap: out = F0*(A+D) + F1*(B+C), componentwise.
__device__ __forceinline__ f32x4 vfilt(const f32x4 A, const f32x4 B,
                                       const f32x4 C, const f32x4 D) {
    f32x4 o;
    o.x = F0 * (A.x + D.x) + F1 * (B.x + C.x);
    o.y = F0 * (A.y + D.y) + F1 * (B.y + C.y);
    o.z = F0 * (A.z + D.z) + F1 * (B.z + C.z);
    o.w = F0 * (A.w + D.w) + F1 * (B.w + C.w);
    return o;
}

__global__ __launch_bounds__(256) void blur_kernel(const float* __restrict__ x,
                                                   float* __restrict__ out) {
    // Stash: per wave, rows {0,62,63} of its strip. 4*3*256*4B = 12 KB.
    __shared__ float stash[4][3][W];
    const int wave  = threadIdx.x >> 6;
    const int lane  = threadIdx.x & 63;
    const int plane = blockIdx.x;
    const float* xp = x + (size_t)plane * (H * W);
    float*       op = out + (size_t)plane * (H * W);
    const int r0  = wave * 64;
    const int col = lane * 4;

    auto loadNT = [&](int i) -> f32x4 {   // single-fetch rows: plain NT stream
        return __builtin_nontemporal_load(
            reinterpret_cast<const f32x4*>(xp + i * W + col));
    };
    auto ldsrow = [&](int w, int s) -> f32x4 {
        return *reinterpret_cast<const f32x4*>(&stash[w][s][col]);
    };
    auto storerow = [&](int i, const f32x4 o) {
        __builtin_nontemporal_store(o, reinterpret_cast<f32x4*>(op + i * W + col));
    };

    // Stash phase: fetch rows r0+{0,62,63} once, publish to LDS.
    {
        f32x4 s0 = loadNT(r0);
        f32x4 s1 = loadNT(r0 + 62);
        f32x4 s2 = loadNT(r0 + 63);
        *reinterpret_cast<f32x4*>(&stash[wave][0][col]) = s0;
        *reinterpret_cast<f32x4*>(&stash[wave][1][col]) = s1;
        *reinterpret_cast<f32x4*>(&stash[wave][2][col]) = s2;
    }
    __syncthreads();   // only barrier; stash is read-only afterwards

    const f32x4 zero{0.f, 0.f, 0.f, 0.f};

    // Window prime: rows r0-2, r0-1 come from wave-1's stash (rows 62,63),
    // row r0 from own stash. Wave 0: zero-pad (hfilt(0)=0).
    f32x4 A = (wave > 0) ? hfilt(ldsrow(wave - 1, 1), lane) : zero;
    f32x4 B = (wave > 0) ? hfilt(ldsrow(wave - 1, 2), lane) : zero;
    f32x4 C = hfilt(ldsrow(wave, 0), lane);

    // Two 4-row raw-input buffers, 8 rows in flight (named: static indexing).
    // Rows r0+1..r0+8 are all in-plane and non-special.
    f32x4 a0 = loadNT(r0 + 1), a1 = loadNT(r0 + 2),
          a2 = loadNT(r0 + 3), a3 = loadNT(r0 + 4);
    f32x4 b0 = loadNT(r0 + 5), b1 = loadNT(r0 + 6),
          b2 = loadNT(r0 + 7), b3 = loadNT(r0 + 8);

#pragma unroll
    for (int g = 0; g < 8; ++g) {
        const int base = r0 + 8 * g;   // outputs base..base+7 this group

        // ---- half 1: consume a (rows base+1..base+4), outputs base..base+3
        f32x4 D0 = hfilt(a0, lane), D1 = hfilt(a1, lane),
              D2 = hfilt(a2, lane), D3 = hfilt(a3, lane);
        f32x4 o0 = vfilt(A,  B,  C,  D0);
        f32x4 o1 = vfilt(B,  C,  D0, D1);
        f32x4 o2 = vfilt(C,  D0, D1, D2);
        f32x4 o3 = vfilt(D0, D1, D2, D3);
        A = D1; B = D2; C = D3;
        if (g < 7) {  // refill a: rows base+9..base+12 (in-plane, non-special)
            a0 = loadNT(base + 9);  a1 = loadNT(base + 10);
            a2 = loadNT(base + 11); a3 = loadNT(base + 12);
        }
        storerow(base,     o0); storerow(base + 1, o1);
        storerow(base + 2, o2); storerow(base + 3, o3);

        // ---- half 2: consume b (rows base+5..base+8), outputs base+4..base+7
        f32x4 E0 = hfilt(b0, lane), E1 = hfilt(b1, lane),
              E2 = hfilt(b2, lane), E3 = hfilt(b3, lane);
        f32x4 p0 = vfilt(A,  B,  C,  E0);
        f32x4 p1 = vfilt(B,  C,  E0, E1);
        f32x4 p2 = vfilt(C,  E0, E1, E2);
        f32x4 p3 = vfilt(E0, E1, E2, E3);
        A = E1; B = E2; C = E3;
        if (g == 6) {
            // refill b: rows 61,62,63,64. 62,63 from own stash; 64 from
            // wave+1's stash (row 0 of next strip) or zero-pad at plane end.
            b0 = loadNT(base + 13);                       // row r0+61
            b1 = ldsrow(wave, 1);                         // row r0+62
            b2 = ldsrow(wave, 2);                         // row r0+63
            b3 = (wave < 3) ? ldsrow(wave + 1, 0) : zero; // row r0+64
        } else if (g < 7) {  // rows base+13..base+16 (in-plane, non-special)
            b0 = loadNT(base + 13); b1 = loadNT(base + 14);
            b2 = loadNT(base + 15); b3 = loadNT(base + 16);
        }
        storerow(base + 4, p0); storerow(base + 5, p1);
        storerow(base + 6, p2); storerow(base + 7, p3);
    }
}

extern "C" void kernel_launch(void* const* d_in, const int* in_sizes, int n_in,
                              void* d_out, int out_size, void* d_ws, size_t ws_size,
                              hipStream_t stream) {
    const float* x = (const float*)d_in[0];
    float* o = (float*)d_out;
    const int planes = in_sizes[0] / (H * W);  // N*C = 2048
    blur_kernel<<<planes, 256, 0, stream>>>(x, o);
}